// Round 2
// baseline (256.726 us; speedup 1.0000x reference)
//
#include <hip/hip_runtime.h>
#include <hip/hip_bf16.h>

#define NN 256
#define CC 128
#define HH 4
#define CHD 32

typedef __attribute__((ext_vector_type(8))) short bf16x8;
typedef __attribute__((ext_vector_type(4))) float f32x4;

static __device__ __forceinline__ short f2bf(float f) {
  union { float f; unsigned u; } un; un.f = f;
  unsigned r = un.u + 0x7fff + ((un.u >> 16) & 1);
  return (short)(r >> 16);
}
static __device__ __forceinline__ float bf2f(short s) {
  union { unsigned u; float f; } un;
  un.u = ((unsigned)(unsigned short)s) << 16;
  return un.f;
}

// ---------------- Kernel A: fused projections q,k,v,gate ----------------
// grid 1024, block 256 (4 waves). Wave w handles projection w for 64 rows.
__global__ __launch_bounds__(256) void proj_kernel(
    const float* __restrict__ pair,
    const float* __restrict__ Wq, const float* __restrict__ bq,
    const float* __restrict__ Wk, const float* __restrict__ bk,
    const float* __restrict__ Wv, const float* __restrict__ bv,
    const float* __restrict__ Wg, const float* __restrict__ bg,
    short* __restrict__ qo, short* __restrict__ ko,
    short* __restrict__ vo, short* __restrict__ go)
{
  const int wid  = threadIdx.x >> 6;
  const int lane = threadIdx.x & 63;
  const int g    = lane >> 4;
  const int t16  = lane & 15;

  const float* W; const float* bias;
  if (wid == 0)      { W = Wq; bias = bq; }
  else if (wid == 1) { W = Wk; bias = bk; }
  else if (wid == 2) { W = Wv; bias = bv; }
  else               { W = Wg; bias = bg; }

  // B fragments: B[k][n] = W[n][k]; lane: n = t16 (col-tile t), k = g*8+j (+32*kc)
  bf16x8 Bf[8][4];
  #pragma unroll
  for (int t = 0; t < 8; ++t) {
    const float* wr = W + (t*16 + t16) * CC;
    #pragma unroll
    for (int kc = 0; kc < 4; ++kc) {
      const float* p = wr + kc*32 + g*8;
      bf16x8 b;
      #pragma unroll
      for (int j = 0; j < 8; ++j) b[j] = f2bf(p[j]);
      Bf[t][kc] = b;
    }
  }
  float bcol[8];
  #pragma unroll
  for (int t = 0; t < 8; ++t) bcol[t] = bias[t*16 + t16];

  const int row0 = blockIdx.x * 64;
  #pragma unroll 1
  for (int ch = 0; ch < 4; ++ch) {
    const int rbase = row0 + ch*16;
    bf16x8 Af[4];
    #pragma unroll
    for (int kc = 0; kc < 4; ++kc) {
      const float* p = pair + (size_t)(rbase + t16) * CC + kc*32 + g*8;
      bf16x8 a;
      #pragma unroll
      for (int j = 0; j < 8; ++j) a[j] = f2bf(p[j]);
      Af[kc] = a;
    }
    f32x4 acc[8];
    #pragma unroll
    for (int t = 0; t < 8; ++t) acc[t] = f32x4{0.f, 0.f, 0.f, 0.f};
    #pragma unroll
    for (int kc = 0; kc < 4; ++kc)
      #pragma unroll
      for (int t = 0; t < 8; ++t)
        acc[t] = __builtin_amdgcn_mfma_f32_16x16x32_bf16(Af[kc], Bf[t][kc], acc[t], 0, 0, 0);

    #pragma unroll
    for (int t = 0; t < 8; ++t) {
      const int col = t*16 + t16;
      #pragma unroll
      for (int r = 0; r < 4; ++r) {
        const int m = rbase + g*4 + r;
        float v = acc[t][r] + bcol[t];
        if (wid == 3) {
          float s = 1.f / (1.f + __expf(-v));
          go[(size_t)m * CC + col] = f2bf(s);
        } else {
          const int i = m >> 8, j = m & 255;
          const int h = col >> 5, c = col & 31;
          const size_t dst = (size_t)(i*HH + h) * (NN*CHD) + j*CHD + c;
          short b = f2bf(v);
          if (wid == 0)      qo[dst] = b;
          else if (wid == 1) ko[dst] = b;
          else               vo[dst] = b;
        }
      }
    }
  }
}

// ---------------- Kernel B: per-(i,h) attention ----------------
// grid 1024 (i*4+h), block 256 (4 waves); wave handles 64 q-rows in 4 chunks of 16.
__global__ __launch_bounds__(256) void attn_kernel(
    const short* __restrict__ qi, const short* __restrict__ ki,
    const short* __restrict__ vi, short* __restrict__ ao)
{
  __shared__ short Kl[256*56];      // [kpos][ch], stride 56 (16B-aligned rows, 2-way banks)
  __shared__ short Vt[32*264];      // [ch][kpos], stride 264
  __shared__ short Pl[4][16*264];   // per-wave P buffer [qrow][kpos], stride 264

  const int bid  = blockIdx.x;
  const int i    = bid >> 2, h = bid & 3;
  const size_t base = (size_t)(i*HH + h) * (NN*CHD);
  const int tid  = threadIdx.x;
  const int wid  = tid >> 6, lane = tid & 63;
  const int g    = lane >> 4, t16 = lane & 15;

  { // stage K (row per thread) and V transposed
    const short* kr = ki + base + (size_t)tid * CHD;
    #pragma unroll
    for (int u = 0; u < 4; ++u)
      *(bf16x8*)&Kl[tid*56 + u*8] = *(const bf16x8*)(kr + u*8);
    const short* vr = vi + base + (size_t)tid * CHD;
    #pragma unroll
    for (int u = 0; u < 4; ++u) {
      bf16x8 v8 = *(const bf16x8*)(vr + u*8);
      #pragma unroll
      for (int e = 0; e < 8; ++e)
        Vt[(u*8 + e)*264 + tid] = v8[e];
    }
  }
  __syncthreads();

  const float cs = 0.17677669529663689f * 1.4426950408889634f; // scale * log2(e)

  #pragma unroll 1
  for (int c4 = 0; c4 < 4; ++c4) {
    const int j0 = wid*64 + c4*16;
    bf16x8 qf = *(const bf16x8*)(qi + base + (size_t)(j0 + t16)*CHD + g*8);

    f32x4 s[16];
    #pragma unroll
    for (int t = 0; t < 16; ++t) {
      bf16x8 kf = *(const bf16x8*)&Kl[(t*16 + t16)*56 + g*8];
      s[t] = __builtin_amdgcn_mfma_f32_16x16x32_bf16(qf, kf, f32x4{0.f,0.f,0.f,0.f}, 0, 0, 0);
    }

    float mx[4], sm[4];
    #pragma unroll
    for (int r = 0; r < 4; ++r) {
      float m = s[0][r];
      #pragma unroll
      for (int t = 1; t < 16; ++t) m = fmaxf(m, s[t][r]);
      m = fmaxf(m, __shfl_xor(m, 1));
      m = fmaxf(m, __shfl_xor(m, 2));
      m = fmaxf(m, __shfl_xor(m, 4));
      m = fmaxf(m, __shfl_xor(m, 8));
      mx[r] = m;
    }
    #pragma unroll
    for (int t = 0; t < 16; ++t) {
      f32x4 v = s[t];
      #pragma unroll
      for (int r = 0; r < 4; ++r) v[r] = exp2f((v[r] - mx[r]) * cs);
      s[t] = v;
    }
    #pragma unroll
    for (int r = 0; r < 4; ++r) {
      float sum = 0.f;
      #pragma unroll
      for (int t = 0; t < 16; ++t) sum += s[t][r];
      sum += __shfl_xor(sum, 1);
      sum += __shfl_xor(sum, 2);
      sum += __shfl_xor(sum, 4);
      sum += __shfl_xor(sum, 8);
      sm[r] = 1.f / sum;
    }

    // write unnormalized P to per-wave LDS (re-layout C->A fragment)
    short* P = &Pl[wid][0];
    asm volatile("s_waitcnt lgkmcnt(0)" ::: "memory"); // WAR vs prev chunk's reads
    #pragma unroll
    for (int t = 0; t < 16; ++t)
      #pragma unroll
      for (int r = 0; r < 4; ++r)
        P[(g*4 + r)*264 + t*16 + t16] = f2bf(s[t][r]);
    asm volatile("s_waitcnt lgkmcnt(0)" ::: "memory"); // writes visible to own wave reads

    bf16x8 pa[8];
    #pragma unroll
    for (int kc = 0; kc < 8; ++kc)
      pa[kc] = *(const bf16x8*)&P[t16*264 + kc*32 + g*8];

    f32x4 o0 = f32x4{0.f,0.f,0.f,0.f};
    f32x4 o1 = f32x4{0.f,0.f,0.f,0.f};
    #pragma unroll
    for (int kc = 0; kc < 8; ++kc) {
      bf16x8 v0 = *(const bf16x8*)&Vt[(t16)*264 + kc*32 + g*8];
      bf16x8 v1 = *(const bf16x8*)&Vt[(16 + t16)*264 + kc*32 + g*8];
      o0 = __builtin_amdgcn_mfma_f32_16x16x32_bf16(pa[kc], v0, o0, 0, 0, 0);
      o1 = __builtin_amdgcn_mfma_f32_16x16x32_bf16(pa[kc], v1, o1, 0, 0, 0);
    }

    #pragma unroll
    for (int r = 0; r < 4; ++r) {
      const int j = j0 + g*4 + r;
      const size_t rowb = (size_t)(i*NN + j) * CC + h*CHD;
      ao[rowb + t16]      = f2bf(o0[r] * sm[r]);
      ao[rowb + 16 + t16] = f2bf(o1[r] * sm[r]);
    }
  }
}

// ---------------- Kernel C: gate*attn @ Wo^T + residual + LayerNorm ----------------
// grid 1024, block 256 (4 waves), wave = 16 rows.
__global__ __launch_bounds__(256) void out_kernel(
    const short* __restrict__ ai, const short* __restrict__ gi,
    const float* __restrict__ Wo, const float* __restrict__ bo,
    const float* __restrict__ pair, const float* __restrict__ gamma,
    const float* __restrict__ beta, float* __restrict__ out)
{
  __shared__ short Wl[128*136];
  const int tid = threadIdx.x;
  const int wid = tid >> 6, lane = tid & 63;
  const int g = lane >> 4, t16 = lane & 15;

  { // stage Wo as bf16 (padded stride 136)
    const int row = tid >> 1, c0 = (tid & 1) * 64;
    const float* src = Wo + row*CC + c0;
    #pragma unroll
    for (int u = 0; u < 8; ++u) {
      bf16x8 b;
      #pragma unroll
      for (int j = 0; j < 8; ++j) b[j] = f2bf(src[u*8 + j]);
      *(bf16x8*)&Wl[row*136 + c0 + u*8] = b;
    }
  }
  __syncthreads();

  const int m0 = blockIdx.x*64 + wid*16;

  bf16x8 af[4];
  #pragma unroll
  for (int kc = 0; kc < 4; ++kc) {
    const short* ar = ai + (size_t)(m0 + t16)*CC + kc*32 + g*8;
    const short* gr = gi + (size_t)(m0 + t16)*CC + kc*32 + g*8;
    bf16x8 a8 = *(const bf16x8*)ar;
    bf16x8 g8 = *(const bf16x8*)gr;
    bf16x8 o;
    #pragma unroll
    for (int j = 0; j < 8; ++j) o[j] = f2bf(bf2f(a8[j]) * bf2f(g8[j]));
    af[kc] = o;
  }

  f32x4 acc[8];
  #pragma unroll
  for (int t = 0; t < 8; ++t) acc[t] = f32x4{0.f,0.f,0.f,0.f};
  #pragma unroll
  for (int kc = 0; kc < 4; ++kc)
    #pragma unroll
    for (int t = 0; t < 8; ++t) {
      bf16x8 bfr = *(const bf16x8*)&Wl[(t*16 + t16)*136 + kc*32 + g*8];
      acc[t] = __builtin_amdgcn_mfma_f32_16x16x32_bf16(af[kc], bfr, acc[t], 0, 0, 0);
    }

  float val[8][4];
  #pragma unroll
  for (int t = 0; t < 8; ++t) {
    const int col = t*16 + t16;
    const float b = bo[col];
    #pragma unroll
    for (int r = 0; r < 4; ++r) {
      const int m = m0 + g*4 + r;
      val[t][r] = acc[t][r] + b + pair[(size_t)m*CC + col];
    }
  }
  #pragma unroll
  for (int r = 0; r < 4; ++r) {
    float s = 0.f;
    #pragma unroll
    for (int t = 0; t < 8; ++t) s += val[t][r];
    s += __shfl_xor(s, 1); s += __shfl_xor(s, 2);
    s += __shfl_xor(s, 4); s += __shfl_xor(s, 8);
    const float mu = s * (1.f/128.f);
    float sq = 0.f;
    #pragma unroll
    for (int t = 0; t < 8; ++t) { float d = val[t][r] - mu; sq += d*d; }
    sq += __shfl_xor(sq, 1); sq += __shfl_xor(sq, 2);
    sq += __shfl_xor(sq, 4); sq += __shfl_xor(sq, 8);
    const float rstd = rsqrtf(sq * (1.f/128.f) + 1e-5f);
    const int m = m0 + g*4 + r;
    #pragma unroll
    for (int t = 0; t < 8; ++t) {
      const int col = t*16 + t16;
      out[(size_t)m*CC + col] = (val[t][r] - mu) * rstd * gamma[col] + beta[col];
    }
  }
}

extern "C" void kernel_launch(void* const* d_in, const int* in_sizes, int n_in,
                              void* d_out, int out_size, void* d_ws, size_t ws_size,
                              hipStream_t stream) {
  const float* pair  = (const float*)d_in[0];
  const float* Wq    = (const float*)d_in[1];
  const float* bq    = (const float*)d_in[2];
  const float* Wk    = (const float*)d_in[3];
  const float* bk    = (const float*)d_in[4];
  const float* Wv    = (const float*)d_in[5];
  const float* bv    = (const float*)d_in[6];
  const float* Wg    = (const float*)d_in[7];
  const float* bg    = (const float*)d_in[8];
  const float* Wo    = (const float*)d_in[9];
  const float* bo    = (const float*)d_in[10];
  const float* gamma = (const float*)d_in[11];
  const float* beta  = (const float*)d_in[12];
  float* out = (float*)d_out;

  short* q_ws = (short*)d_ws;            // [i][h][j][ch] bf16
  short* k_ws = q_ws + 8388608;
  short* v_ws = k_ws + 8388608;
  short* g_ws = v_ws + 8388608;          // [m][128] bf16 (sigmoid applied)
  short* a_ws = g_ws + 8388608;          // [m][128] bf16 attention out

  hipLaunchKernelGGL(proj_kernel, dim3(1024), dim3(256), 0, stream,
                     pair, Wq, bq, Wk, bk, Wv, bv, Wg, bg, q_ws, k_ws, v_ws, g_ws);
  hipLaunchKernelGGL(attn_kernel, dim3(1024), dim3(256), 0, stream,
                     q_ws, k_ws, v_ws, a_ws);
  hipLaunchKernelGGL(out_kernel, dim3(1024), dim3(256), 0, stream,
                     a_ws, g_ws, Wo, bo, pair, gamma, beta, out);
}

// Round 3
// 208.047 us; speedup vs baseline: 1.2340x; 1.2340x over previous
//
#include <hip/hip_runtime.h>
#include <hip/hip_bf16.h>

#define NN 256
#define CC 128
#define HH 4
#define CHD 32

typedef __attribute__((ext_vector_type(8))) short bf16x8;
typedef __attribute__((ext_vector_type(4))) short bf16x4;
typedef __attribute__((ext_vector_type(4))) float f32x4;

static __device__ __forceinline__ short f2bf(float f) {
  union { float f; unsigned u; } un; un.f = f;
  unsigned r = un.u + 0x7fff + ((un.u >> 16) & 1);
  return (short)(r >> 16);
}
static __device__ __forceinline__ float bf2f(short s) {
  union { unsigned u; float f; } un;
  un.u = ((unsigned)(unsigned short)s) << 16;
  return un.f;
}

// ---------------- Kernel P: pre-pack weights to bf16 A-fragment layout ----------
// wpk[w][t][kc][lane][8] : 16B chunk = W[t*16 + (lane&15)][kc*32 + (lane>>4)*8 ..+7]
// w: 0=q 1=k 2=v 3=g 4=o. grid 40 x 256 (10240 chunks).
__global__ void prep_kernel(const float* __restrict__ Wq, const float* __restrict__ Wk,
                            const float* __restrict__ Wv, const float* __restrict__ Wg,
                            const float* __restrict__ Wo, short* __restrict__ wpk)
{
  const int c = blockIdx.x * 256 + threadIdx.x;   // 0..10239
  const int w = c >> 11;
  const int rem = c & 2047;
  const int t = rem >> 8;
  const int kc = (rem >> 6) & 3;
  const int lane = rem & 63;
  const float* W = (w == 0) ? Wq : (w == 1) ? Wk : (w == 2) ? Wv : (w == 3) ? Wg : Wo;
  const int row = t * 16 + (lane & 15);
  const int col = kc * 32 + (lane >> 4) * 8;
  const float* src = W + row * CC + col;
  bf16x8 b;
  #pragma unroll
  for (int j = 0; j < 8; ++j) b[j] = f2bf(src[j]);
  *(bf16x8*)(wpk + (size_t)c * 8) = b;
}

// ---------------- Kernel A: fused projections q,k,v,gate ----------------
// grid 512 (128 rows each), block 256 (4 waves). Wave w = projection w, 128 rows.
// Computes D = mfma(W, pair) (transposed C): lane holds 4 consecutive out-cols of
// one row -> packed 8B stores. Outputs in [m][C] layout.
__global__ __launch_bounds__(256) void proj_kernel(
    const float* __restrict__ pair, const short* __restrict__ wpk,
    const float* __restrict__ bq, const float* __restrict__ bk,
    const float* __restrict__ bv, const float* __restrict__ bg,
    short* __restrict__ qo, short* __restrict__ ko,
    short* __restrict__ vo, short* __restrict__ go)
{
  const int wid  = threadIdx.x >> 6;
  const int lane = threadIdx.x & 63;
  const int g    = lane >> 4;
  const int t16  = lane & 15;

  const short* wsrc = wpk + (size_t)wid * 16384;
  bf16x8 wf[8][4];
  #pragma unroll
  for (int t = 0; t < 8; ++t)
    #pragma unroll
    for (int kc = 0; kc < 4; ++kc)
      wf[t][kc] = *(const bf16x8*)(wsrc + ((t*4 + kc)*64 + lane) * 8);

  const float* bias = (wid == 0) ? bq : (wid == 1) ? bk : (wid == 2) ? bv : bg;
  f32x4 bcol[8];
  #pragma unroll
  for (int t = 0; t < 8; ++t) bcol[t] = *(const f32x4*)(bias + t*16 + g*4);

  short* outp = (wid == 0) ? qo : (wid == 1) ? ko : (wid == 2) ? vo : go;
  const int row0 = blockIdx.x * 128;

  #pragma unroll 1
  for (int ch = 0; ch < 8; ++ch) {
    const int rbase = row0 + ch * 16;
    bf16x8 pf[4];
    #pragma unroll
    for (int kc = 0; kc < 4; ++kc) {
      const float* p = pair + (size_t)(rbase + t16) * CC + kc*32 + g*8;
      bf16x8 a;
      #pragma unroll
      for (int j = 0; j < 8; ++j) a[j] = f2bf(p[j]);
      pf[kc] = a;
    }
    f32x4 acc[8];
    #pragma unroll
    for (int t = 0; t < 8; ++t) acc[t] = f32x4{0.f, 0.f, 0.f, 0.f};
    #pragma unroll
    for (int kc = 0; kc < 4; ++kc)
      #pragma unroll
      for (int t = 0; t < 8; ++t)
        acc[t] = __builtin_amdgcn_mfma_f32_16x16x32_bf16(wf[t][kc], pf[kc], acc[t], 0, 0, 0);

    // D[n][m]: m = rbase+t16 (row), n = t*16+g*4+r (col)
    const size_t rowoff = (size_t)(rbase + t16) * CC;
    #pragma unroll
    for (int t = 0; t < 8; ++t) {
      f32x4 v;
      #pragma unroll
      for (int r = 0; r < 4; ++r) v[r] = acc[t][r] + bcol[t][r];
      if (wid == 3) {
        #pragma unroll
        for (int r = 0; r < 4; ++r) v[r] = 1.f / (1.f + __expf(-v[r]));
      }
      bf16x4 pk;
      #pragma unroll
      for (int r = 0; r < 4; ++r) pk[r] = f2bf(v[r]);
      *(bf16x4*)(outp + rowoff + t*16 + g*4) = pk;
    }
  }
}

// ---------------- Kernel B: per-(i,h) attention ----------------
// grid 1024 (i*4+h), block 256 (4 waves); wave = 64 q-rows in 4 chunks of 16.
// QK^T computed transposed: s = mfma(K, Q) -> lane owns 64 scores of q-row t16.
// PV computed transposed: o = mfma(V^T, P^T) -> lane owns 4 consecutive ch of its q.
// ao aliases v_ws (V fully staged to LDS before first write).
__global__ __launch_bounds__(256) void attn_kernel(
    const short* __restrict__ qi, const short* __restrict__ ki,
    const short* __restrict__ vi, short* __restrict__ ao)
{
  __shared__ short Vt[32*264];      // [ch][kpos], stride 264
  __shared__ short Pl[4][16*264];   // per-wave P [qrow][kpos], stride 264

  const int bid  = blockIdx.x;
  const int i    = bid >> 2, h = bid & 3;
  const size_t pbase = (size_t)i * NN * CC + h * CHD;  // row j elem: pbase + j*CC
  const int tid  = threadIdx.x;
  const int wid  = tid >> 6, lane = tid & 63;
  const int g    = lane >> 4, t16 = lane & 15;

  { // stage V transposed (kpos = tid)
    const short* vr = vi + pbase + (size_t)tid * CC;
    #pragma unroll
    for (int u = 0; u < 4; ++u) {
      bf16x8 v8 = *(const bf16x8*)(vr + u*8);
      #pragma unroll
      for (int e = 0; e < 8; ++e)
        Vt[(u*8 + e)*264 + tid] = v8[e];
    }
  }
  __syncthreads();

  const float cs = 0.17677669529663689f * 1.4426950408889634f; // scale * log2(e)

  #pragma unroll 1
  for (int c4 = 0; c4 < 4; ++c4) {
    const int q0 = wid*64 + c4*16;
    bf16x8 qf = *(const bf16x8*)(qi + pbase + (size_t)(q0 + t16)*CC + g*8);

    f32x4 s[16];
    #pragma unroll
    for (int t = 0; t < 16; ++t) {
      bf16x8 kf = *(const bf16x8*)(ki + pbase + (size_t)(t*16 + t16)*CC + g*8);
      s[t] = __builtin_amdgcn_mfma_f32_16x16x32_bf16(kf, qf, f32x4{0.f,0.f,0.f,0.f}, 0, 0, 0);
    }

    // softmax for q-row = t16: 64 in-lane values + reduce over g (lane bits 4,5)
    f32x4 m4 = s[0];
    #pragma unroll
    for (int t = 1; t < 16; ++t)
      #pragma unroll
      for (int r = 0; r < 4; ++r) m4[r] = fmaxf(m4[r], s[t][r]);
    float m = fmaxf(fmaxf(m4[0], m4[1]), fmaxf(m4[2], m4[3]));
    m = fmaxf(m, __shfl_xor(m, 16));
    m = fmaxf(m, __shfl_xor(m, 32));

    f32x4 s4 = f32x4{0.f,0.f,0.f,0.f};
    #pragma unroll
    for (int t = 0; t < 16; ++t) {
      f32x4 v = s[t];
      #pragma unroll
      for (int r = 0; r < 4; ++r) { v[r] = exp2f((v[r] - m) * cs); s4[r] += v[r]; }
      s[t] = v;
    }
    float sum = (s4[0] + s4[1]) + (s4[2] + s4[3]);
    sum += __shfl_xor(sum, 16);
    sum += __shfl_xor(sum, 32);
    const float sm = 1.f / sum;

    short* P = &Pl[wid][0];
    asm volatile("s_waitcnt lgkmcnt(0)" ::: "memory"); // WAR vs prev chunk's reads
    #pragma unroll
    for (int t = 0; t < 16; ++t) {
      bf16x4 pk;
      #pragma unroll
      for (int r = 0; r < 4; ++r) pk[r] = f2bf(s[t][r]);
      *(bf16x4*)&P[t16*264 + t*16 + g*4] = pk;   // ds_write_b64
    }
    asm volatile("s_waitcnt lgkmcnt(0)" ::: "memory"); // writes land before reads

    bf16x8 pa[8];
    #pragma unroll
    for (int kc = 0; kc < 8; ++kc)
      pa[kc] = *(const bf16x8*)&P[t16*264 + kc*32 + g*8];

    f32x4 o0 = f32x4{0.f,0.f,0.f,0.f};
    f32x4 o1 = f32x4{0.f,0.f,0.f,0.f};
    #pragma unroll
    for (int kc = 0; kc < 8; ++kc) {
      bf16x8 v0 = *(const bf16x8*)&Vt[t16*264 + kc*32 + g*8];
      bf16x8 v1 = *(const bf16x8*)&Vt[(16 + t16)*264 + kc*32 + g*8];
      o0 = __builtin_amdgcn_mfma_f32_16x16x32_bf16(v0, pa[kc], o0, 0, 0, 0);
      o1 = __builtin_amdgcn_mfma_f32_16x16x32_bf16(v1, pa[kc], o1, 0, 0, 0);
    }

    // D[ch][q]: q = q0+t16 (lane's own row, sm valid), ch = tile*16 + g*4 + r
    const size_t orow = pbase + (size_t)(q0 + t16) * CC;
    bf16x4 pk0, pk1;
    #pragma unroll
    for (int r = 0; r < 4; ++r) {
      pk0[r] = f2bf(o0[r] * sm);
      pk1[r] = f2bf(o1[r] * sm);
    }
    *(bf16x4*)(ao + orow + g*4)      = pk0;
    *(bf16x4*)(ao + orow + 16 + g*4) = pk1;
  }
}

// ---------------- Kernel C: gate*attn @ Wo^T + residual + LayerNorm ----------------
// grid 1024 (64 rows), block 256 (4 waves, wave = 16 rows). Transposed-C MFMA ->
// float4 packed loads/stores; LN reduce in-lane + 2 shuffles.
__global__ __launch_bounds__(256) void out_kernel(
    const short* __restrict__ ai, const short* __restrict__ gi,
    const short* __restrict__ wpk_o, const float* __restrict__ bo,
    const float* __restrict__ pair, const float* __restrict__ gamma,
    const float* __restrict__ beta, float* __restrict__ out)
{
  __shared__ short Wl[16384];
  const int tid = threadIdx.x;
  const int wid = tid >> 6, lane = tid & 63;
  const int g = lane >> 4, t16 = lane & 15;

  #pragma unroll
  for (int it = 0; it < 8; ++it) {   // stage prepacked Wo (bf16) -> LDS, coalesced
    const int c = it*256 + tid;
    *(bf16x8*)&Wl[c*8] = *(const bf16x8*)(wpk_o + (size_t)c*8);
  }
  __syncthreads();

  const int m0 = blockIdx.x*64 + wid*16;
  const size_t rowoff = (size_t)(m0 + t16) * CC;

  bf16x8 xf[4];
  #pragma unroll
  for (int kc = 0; kc < 4; ++kc) {
    bf16x8 a8 = *(const bf16x8*)(ai + rowoff + kc*32 + g*8);
    bf16x8 g8 = *(const bf16x8*)(gi + rowoff + kc*32 + g*8);
    bf16x8 o;
    #pragma unroll
    for (int j = 0; j < 8; ++j) o[j] = f2bf(bf2f(a8[j]) * bf2f(g8[j]));
    xf[kc] = o;
  }

  f32x4 acc[8];
  #pragma unroll
  for (int t = 0; t < 8; ++t) acc[t] = f32x4{0.f,0.f,0.f,0.f};
  #pragma unroll
  for (int kc = 0; kc < 4; ++kc)
    #pragma unroll
    for (int t = 0; t < 8; ++t) {
      bf16x8 wfr = *(const bf16x8*)&Wl[((t*4 + kc)*64 + lane)*8];
      acc[t] = __builtin_amdgcn_mfma_f32_16x16x32_bf16(wfr, xf[kc], acc[t], 0, 0, 0);
    }

  // D[n][m]: m = m0+t16 (row), n = t*16+g*4+r (col)
  float val[8][4];
  #pragma unroll
  for (int t = 0; t < 8; ++t) {
    f32x4 b4 = *(const f32x4*)(bo + t*16 + g*4);
    f32x4 p4 = *(const f32x4*)(pair + rowoff + t*16 + g*4);
    #pragma unroll
    for (int r = 0; r < 4; ++r) val[t][r] = acc[t][r] + b4[r] + p4[r];
  }
  float sum = 0.f;
  #pragma unroll
  for (int t = 0; t < 8; ++t)
    #pragma unroll
    for (int r = 0; r < 4; ++r) sum += val[t][r];
  sum += __shfl_xor(sum, 16); sum += __shfl_xor(sum, 32);
  const float mu = sum * (1.f/128.f);
  float sq = 0.f;
  #pragma unroll
  for (int t = 0; t < 8; ++t)
    #pragma unroll
    for (int r = 0; r < 4; ++r) { float d = val[t][r] - mu; sq += d*d; }
  sq += __shfl_xor(sq, 16); sq += __shfl_xor(sq, 32);
  const float rstd = rsqrtf(sq * (1.f/128.f) + 1e-5f);

  #pragma unroll
  for (int t = 0; t < 8; ++t) {
    f32x4 g4 = *(const f32x4*)(gamma + t*16 + g*4);
    f32x4 b4 = *(const f32x4*)(beta  + t*16 + g*4);
    f32x4 o4;
    #pragma unroll
    for (int r = 0; r < 4; ++r) o4[r] = (val[t][r] - mu) * rstd * g4[r] + b4[r];
    *(f32x4*)(out + rowoff + t*16 + g*4) = o4;
  }
}

extern "C" void kernel_launch(void* const* d_in, const int* in_sizes, int n_in,
                              void* d_out, int out_size, void* d_ws, size_t ws_size,
                              hipStream_t stream) {
  const float* pair  = (const float*)d_in[0];
  const float* Wq    = (const float*)d_in[1];
  const float* bq    = (const float*)d_in[2];
  const float* Wk    = (const float*)d_in[3];
  const float* bk    = (const float*)d_in[4];
  const float* Wv    = (const float*)d_in[5];
  const float* bv    = (const float*)d_in[6];
  const float* Wg    = (const float*)d_in[7];
  const float* bg    = (const float*)d_in[8];
  const float* Wo    = (const float*)d_in[9];
  const float* bo    = (const float*)d_in[10];
  const float* gamma = (const float*)d_in[11];
  const float* beta  = (const float*)d_in[12];
  float* out = (float*)d_out;

  short* wpk  = (short*)d_ws;            // 5 * 16384 bf16, prepacked weights
  short* q_ws = wpk + 81920;             // [m][C] bf16
  short* k_ws = q_ws + 8388608;
  short* v_ws = k_ws + 8388608;          // also reused as attention output
  short* g_ws = v_ws + 8388608;          // [m][C] bf16 (sigmoid applied)
  short* a_ws = v_ws;                    // attn out aliases V (safe: V LDS-staged first)

  hipLaunchKernelGGL(prep_kernel, dim3(40), dim3(256), 0, stream,
                     Wq, Wk, Wv, Wg, Wo, wpk);
  hipLaunchKernelGGL(proj_kernel, dim3(512), dim3(256), 0, stream,
                     pair, wpk, bq, bk, bv, bg, q_ws, k_ws, v_ws, g_ws);
  hipLaunchKernelGGL(attn_kernel, dim3(1024), dim3(256), 0, stream,
                     q_ws, k_ws, v_ws, a_ws);
  hipLaunchKernelGGL(out_kernel, dim3(1024), dim3(256), 0, stream,
                     a_ws, g_ws, wpk + 4*16384, bo, pair, gamma, beta, out);
}